// Round 11
// baseline (113.717 us; speedup 1.0000x reference)
//
#include <hip/hip_runtime.h>
#include <hip/hip_cooperative_groups.h>
#include <hip/hip_bf16.h>
#include <math.h>

namespace cg = cooperative_groups;

#define NB 32      // B
#define NV 1024    // V
#define NFT 16     // F
#define NA 32      // A
#define NP 64      // P
#define NOUT 128   // NF
#define NC 96      // C = P + A
#define NC2 192    // 2C

#define NSPLIT 16            // V splits
#define VPB 64               // rows per phase-1 slice
#define MB 64                // rows per phase-3 tile

typedef __attribute__((ext_vector_type(8))) short bf16x8;
typedef __attribute__((ext_vector_type(4))) float f32x4;

#define SWZ(r, k)  (((r) << 6) + ((k) ^ (((r) & 7) << 3)))
#define SWZB(n, k) (((n) << 6) + ((k) ^ (((((n) >> 3) & 7) ^ ((n) & 7)) << 3)))

__device__ inline void f2hl(float v, ushort& h, ushort& l) {
    __hip_bfloat16 hb = __float2bfloat16(v);
    float hf = __bfloat162float(hb);
    __hip_bfloat16 lb = __float2bfloat16(v - hf);
    h = *(ushort*)&hb;
    l = *(ushort*)&lb;
}

// LDS union across phases (max 48.5 KB; 256 blocks -> 1 block/CU)
struct SmP1 { float xs[VPB][NFT]; float fs[VPB][NC]; };                    // 28 KB
struct SmP2 { float aggL[4][NC2]; };                                       // 3 KB
struct SmP3 { ushort AsH[MB * 64]; ushort AsL[MB * 64];
              ushort BsH[NOUT * 64]; ushort BsL[NOUT * 64]; float bs[NOUT]; }; // 48.5 KB
union SmemU { SmP1 p1; SmP2 p2; SmP3 p3; };

__global__ __launch_bounds__(512, 2)
void garnet_fused(const float* __restrict__ x,
                  const float* __restrict__ W_flr,
                  const float* __restrict__ b_flr,
                  const float* __restrict__ W_s,
                  const float* __restrict__ b_s,
                  const float* __restrict__ W_out,
                  const float* __restrict__ b_out,
                  float* __restrict__ ewbuf,
                  float* __restrict__ part,
                  float* __restrict__ Gp,
                  float* __restrict__ out) {
    __shared__ SmemU S;
    cg::grid_group grid = cg::this_grid();
    int bid = blockIdx.x, tid = threadIdx.x;

    // ============ PHASE 1: vertex transform + partial agg (2 slices) =======
    for (int s = 0; s < 2; ++s) {
        int slice = bid * 2 + s;              // 0..511
        int b = slice >> 4, vs = slice & 15;
        int rowbase = b * NV + vs * VPB;

        // stage x: 1024 floats = 256 float4
        if (tid < 256) {
            const float4* xsrc = (const float4*)(x + (size_t)rowbase * NFT);
            ((float4*)S.p1.xs)[tid] = xsrc[tid];
        }
        __syncthreads();

        // phase A: c = tid&127 (<96 active), rh = tid>>7 -> rows rh*16..+15
        {
            int c  = tid & 127;
            int rh = tid >> 7;
            if (c < NC) {
                float Wcol[NFT], bias;
                if (c < NP) {
                    bias = b_flr[c];
#pragma unroll
                    for (int k = 0; k < NFT; ++k) Wcol[k] = W_flr[k * NP + c];
                } else {
                    int a = c - NP;
                    bias = b_s[a];
#pragma unroll
                    for (int k = 0; k < NFT; ++k) Wcol[k] = W_s[k * NA + a];
                }
#pragma unroll
                for (int r0 = 0; r0 < 16; ++r0) {
                    int r = rh * 16 + r0;
                    float xr[NFT];
#pragma unroll
                    for (int q = 0; q < 4; ++q)
                        ((float4*)xr)[q] = ((const float4*)S.p1.xs[r])[q];
                    float acc = bias;
#pragma unroll
                    for (int k = 0; k < NFT; ++k)
                        acc = fmaf(xr[k], Wcol[k], acc);
                    if (c >= NP) {
                        acc = __expf(-acc * acc);
                        ewbuf[(size_t)(rowbase + r) * NA + (c - NP)] = acc;
                    }
                    S.p1.fs[r][c] = acc;
                }
            }
        }
        __syncthreads();

        // phase B: thread owns 1a x 6c over all 64 rows
        int a  = tid >> 4;
        int c0 = (tid & 15) * 6;
        int ea = NP + a;

        float sm[6], mx[6];
#pragma unroll
        for (int j = 0; j < 6; ++j) { sm[j] = 0.f; mx[j] = -INFINITY; }

#pragma unroll 4
        for (int r = 0; r < VPB; ++r) {
            float e = S.p1.fs[r][ea];
            float2 fA = *(const float2*)&S.p1.fs[r][c0];
            float2 fB = *(const float2*)&S.p1.fs[r][c0 + 2];
            float2 fC = *(const float2*)&S.p1.fs[r][c0 + 4];
            float ff[6] = {fA.x, fA.y, fB.x, fB.y, fC.x, fC.y};
#pragma unroll
            for (int j = 0; j < 6; ++j) {
                float p = e * ff[j];
                sm[j] += p;
                mx[j] = fmaxf(mx[j], p);
            }
        }

        float* pb = part + (size_t)((b * NSPLIT + vs) * NA + a) * NC2;
#pragma unroll
        for (int q = 0; q < 3; ++q) {
            float2 vm = {mx[2 * q], mx[2 * q + 1]};
            float2 vsum = {sm[2 * q], sm[2 * q + 1]};
            *(float2*)&pb[c0 + 2 * q]      = vm;
            *(float2*)&pb[NC + c0 + 2 * q] = vsum;
        }
        __syncthreads();   // protect fs before next slice's phase A
    }

    grid.sync();

    // ============ PHASE 2: combine partials + G matmul (4 units) ===========
    {
        int h = tid >> 7;                 // 0..3
        int t = tid & 127;
        int unit = bid * 4 + h;           // 0..1023
        int b = unit >> 5, a = unit & 31;

        const float* pb = part + (size_t)(b * NSPLIT * NA + a) * NC2;
        const size_t stride = (size_t)NA * NC2;

#pragma unroll
        for (int cell = 0; cell < 2; ++cell) {
            int j = t + cell * 128;
            if (j < NC2) {
                if (j < NC) {
                    float m = -INFINITY;
#pragma unroll
                    for (int vsi = 0; vsi < NSPLIT; ++vsi)
                        m = fmaxf(m, pb[vsi * stride + j]);
                    S.p2.aggL[h][j] = m;
                } else {
                    float sv = 0.f;
#pragma unroll
                    for (int vsi = 0; vsi < NSPLIT; ++vsi)
                        sv += pb[vsi * stride + j];
                    S.p2.aggL[h][j] = sv * (1.0f / (float)NV);
                }
            }
        }
        __syncthreads();

        {
            int n = t;
            const float* wr = W_out + (size_t)(NFT + a * NC2) * NOUT + n;
            float acc = W_out[(size_t)(NFT + NA * NC2 + a) * NOUT + n];
#pragma unroll 8
            for (int c = 0; c < NC2; ++c)
                acc = fmaf(S.p2.aggL[h][c], wr[(size_t)c * NOUT], acc);
            Gp[(size_t)(b * NA + a) * NOUT + n] = acc;
        }
    }

    grid.sync();

    // ============ PHASE 3: MFMA output GEMM + tanh (2 tiles, shared B) =====
    {
        int b = bid & 31;                 // same batch for both tiles

        // ---- stage B^T once: W_head (k=0..15) ----
        if (tid < 256) {
#pragma unroll
            for (int t = 0; t < 2; ++t) {
                int i = tid * 2 + t;
                int k = i >> 5, nq = (i & 31) * 4;
                float4 v = ((const float4*)W_out)[i];
                float vv[4] = {v.x, v.y, v.z, v.w};
#pragma unroll
                for (int j = 0; j < 4; ++j) {
                    ushort h, l;
                    f2hl(vv[j], h, l);
                    S.p3.BsH[SWZB(nq + j, k)] = h;
                    S.p3.BsL[SWZB(nq + j, k)] = l;
                }
            }
            // ---- stage B^T: Gp (k=16..47) ----
            const float4* gp4 = (const float4*)(Gp + (size_t)b * NA * NOUT);
#pragma unroll
            for (int t = 0; t < 4; ++t) {
                int i = tid * 4 + t;
                int a = i >> 5, nq = (i & 31) * 4;
                float4 v = gp4[i];
                int k = 16 + a;
                float vv[4] = {v.x, v.y, v.z, v.w};
#pragma unroll
                for (int j = 0; j < 4; ++j) {
                    ushort h, l;
                    f2hl(vv[j], h, l);
                    S.p3.BsH[SWZB(nq + j, k)] = h;
                    S.p3.BsL[SWZB(nq + j, k)] = l;
                }
            }
            // ---- stage B^T: zero tail (k=48..63) ----
#pragma unroll
            for (int t = 0; t < 4; ++t) {
                int i = tid * 4 + t;
                int n = i >> 3, kq = 48 + (i & 7) * 2;
                *(uint*)&S.p3.BsH[SWZB(n, kq)] = 0u;
                *(uint*)&S.p3.BsL[SWZB(n, kq)] = 0u;
            }
        }
        if (tid < NOUT) S.p3.bs[tid] = b_out[tid];

        for (int s = 0; s < 2; ++s) {
            int tile = s * 256 + bid;
            int rb = tile >> 5;           // 0..15 (s=0: 0..7, s=1: 8..15)
            int rowbase = b * NV + rb * MB;

            if (s) __syncthreads();       // all compute on previous As done

            // ---- stage A: x part (k=0..15) ----
            if (tid < 256) {
                {
                    float4 v = ((const float4*)(x + (size_t)rowbase * NFT))[tid];
                    int r = tid >> 2, kq = (tid & 3) * 4;
                    float vv[4] = {v.x, v.y, v.z, v.w};
                    ushort h[4], l[4];
#pragma unroll
                    for (int j = 0; j < 4; ++j) f2hl(vv[j], h[j], l[j]);
                    *(uint*)&S.p3.AsH[SWZ(r, kq)]     = (uint)h[0] | ((uint)h[1] << 16);
                    *(uint*)&S.p3.AsH[SWZ(r, kq + 2)] = (uint)h[2] | ((uint)h[3] << 16);
                    *(uint*)&S.p3.AsL[SWZ(r, kq)]     = (uint)l[0] | ((uint)l[1] << 16);
                    *(uint*)&S.p3.AsL[SWZ(r, kq + 2)] = (uint)l[2] | ((uint)l[3] << 16);
                }
                // ---- stage A: ew part (k=16..47) ----
                {
                    const float4* es4 = (const float4*)(ewbuf + (size_t)rowbase * NA);
#pragma unroll
                    for (int t = 0; t < 2; ++t) {
                        int i = tid * 2 + t;
                        float4 v = es4[i];
                        int r = i >> 3, kq = 16 + (i & 7) * 4;
                        float vv[4] = {v.x, v.y, v.z, v.w};
                        ushort h[4], l[4];
#pragma unroll
                        for (int j = 0; j < 4; ++j) f2hl(vv[j], h[j], l[j]);
                        *(uint*)&S.p3.AsH[SWZ(r, kq)]     = (uint)h[0] | ((uint)h[1] << 16);
                        *(uint*)&S.p3.AsH[SWZ(r, kq + 2)] = (uint)h[2] | ((uint)h[3] << 16);
                        *(uint*)&S.p3.AsL[SWZ(r, kq)]     = (uint)l[0] | ((uint)l[1] << 16);
                        *(uint*)&S.p3.AsL[SWZ(r, kq + 2)] = (uint)l[2] | ((uint)l[3] << 16);
                    }
                }
                // ---- stage A: zero tail (k=48..63) ----
                {
#pragma unroll
                    for (int t = 0; t < 2; ++t) {
                        int i = tid * 2 + t;
                        int r = i >> 3, kq = 48 + (i & 7) * 2;
                        *(uint*)&S.p3.AsH[SWZ(r, kq)] = 0u;
                        *(uint*)&S.p3.AsL[SWZ(r, kq)] = 0u;
                    }
                }
            }
            __syncthreads();

            // ---- compute: 8 waves = 4 row-groups x 2 n-halves ----
            int w8 = tid >> 6, lane = tid & 63;
            int rgrp = w8 & 3, nh = w8 >> 2;
            int r16 = lane & 15, kg = lane >> 4, k0 = kg * 8;
            int arow = rgrp * 16 + r16;

            bf16x8 AH0 = *(const bf16x8*)&S.p3.AsH[SWZ(arow, k0)];
            bf16x8 AH1 = *(const bf16x8*)&S.p3.AsH[SWZ(arow, 32 + k0)];
            bf16x8 AL0 = *(const bf16x8*)&S.p3.AsL[SWZ(arow, k0)];
            bf16x8 AL1 = *(const bf16x8*)&S.p3.AsL[SWZ(arow, 32 + k0)];

            int orow0 = rowbase + rgrp * 16 + kg * 4;

#pragma unroll
            for (int j = 0; j < 4; ++j) {
                int nt = nh * 4 + j;
                int n = nt * 16 + r16;
                bf16x8 BH0 = *(const bf16x8*)&S.p3.BsH[SWZB(n, k0)];
                bf16x8 BH1 = *(const bf16x8*)&S.p3.BsH[SWZB(n, 32 + k0)];
                bf16x8 BL0 = *(const bf16x8*)&S.p3.BsL[SWZB(n, k0)];
                bf16x8 BL1 = *(const bf16x8*)&S.p3.BsL[SWZB(n, 32 + k0)];
                float bias = S.p3.bs[n];
                f32x4 acc = {bias, bias, bias, bias};
                acc = __builtin_amdgcn_mfma_f32_16x16x32_bf16(AH0, BH0, acc, 0, 0, 0);
                acc = __builtin_amdgcn_mfma_f32_16x16x32_bf16(AL0, BH0, acc, 0, 0, 0);
                acc = __builtin_amdgcn_mfma_f32_16x16x32_bf16(AH0, BL0, acc, 0, 0, 0);
                acc = __builtin_amdgcn_mfma_f32_16x16x32_bf16(AH1, BH1, acc, 0, 0, 0);
                acc = __builtin_amdgcn_mfma_f32_16x16x32_bf16(AL1, BH1, acc, 0, 0, 0);
                acc = __builtin_amdgcn_mfma_f32_16x16x32_bf16(AH1, BL1, acc, 0, 0, 0);
#pragma unroll
                for (int rg = 0; rg < 4; ++rg) {
                    float sv = acc[rg];
                    sv = fminf(fmaxf(sv, -15.f), 15.f);
                    float e = __expf(2.f * sv);
                    out[(size_t)(orow0 + rg) * NOUT + n] =
                        (e - 1.f) * __builtin_amdgcn_rcpf(e + 1.f);
                }
            }
        }
    }
}

// ---------------------------------------------------------------------------
extern "C" void kernel_launch(void* const* d_in, const int* in_sizes, int n_in,
                              void* d_out, int out_size, void* d_ws, size_t ws_size,
                              hipStream_t stream) {
    const float* x     = (const float*)d_in[0];
    const float* W_flr = (const float*)d_in[1];
    const float* b_flr = (const float*)d_in[2];
    const float* W_s   = (const float*)d_in[3];
    const float* b_s   = (const float*)d_in[4];
    const float* W_out = (const float*)d_in[5];
    const float* b_out = (const float*)d_in[6];
    float* out = (float*)d_out;

    // workspace layout (floats)
    float* ewbuf = (float*)d_ws;                              // B*V*32     = 1,048,576
    float* part  = ewbuf + (size_t)NB * NV * NA;              // 512*32*192 = 3,145,728
    float* Gp    = part  + (size_t)NB * NSPLIT * NA * NC2;    // B*A*128    =   131,072

    void* kargs[] = {
        (void*)&x, (void*)&W_flr, (void*)&b_flr, (void*)&W_s, (void*)&b_s,
        (void*)&W_out, (void*)&b_out, (void*)&ewbuf, (void*)&part,
        (void*)&Gp, (void*)&out
    };
    hipLaunchCooperativeKernel((void*)garnet_fused,
                               dim3(256), dim3(512),
                               kargs, 0, stream);
}

// Round 12
// 47.419 us; speedup vs baseline: 2.3981x; 2.3981x over previous
//
#include <hip/hip_runtime.h>
#include <hip/hip_bf16.h>
#include <math.h>

#define NB 32      // B
#define NV 1024    // V
#define NFT 16     // F
#define NA 32      // A
#define NP 64      // P
#define NOUT 128   // NF
#define NC 96      // C = P + A
#define NC2 192    // 2C

#define NSPLIT 16            // V splits
#define VPB 64               // rows per block

typedef __attribute__((ext_vector_type(8))) short bf16x8;
typedef __attribute__((ext_vector_type(4))) float f32x4;

// ---------------------------------------------------------------------------
// K2p: fused vertex transform + partial (max,sum) aggregation.
// grid (B,16) x 512 threads.
//  phase A: c = tid&127 (<96 active), rh = tid>>7 -> rows rh*16..+15.
//  phase B: 2 row-splits x (8 a-quads x 32 c-triples). Per row a thread
//           issues 3 LDS instr (b128 e + float2+b32 f) for 12 products ->
//           per-CU LDS instruction count drops 2.7x vs 1a*6c tiling.
//           rsplit partials merged via comb overlay on dead fs space.
// part layout: part[((b*16+vs)*32 + a)*192 + c] = max ; +96+c = sum
// ---------------------------------------------------------------------------
__global__ __launch_bounds__(512, 2)
void k2p(const float* __restrict__ x,
         const float* __restrict__ W_flr,
         const float* __restrict__ b_flr,
         const float* __restrict__ W_s,
         const float* __restrict__ b_s,
         float* __restrict__ ewbuf,
         float* __restrict__ part) {
    // xs = SM[0..1023], fs = SM[1024..7167]; comb overlays SM[0..6655]
    __shared__ float SM[7168];          // 28 KB
    float (*xs)[NFT] = (float (*)[NFT])SM;
    float (*fs)[NC]  = (float (*)[NC])(SM + 1024);
    float* comb = SM;                   // 256 units * 26 floats = 6656

    int b = blockIdx.x, vs = blockIdx.y, tid = threadIdx.x;
    int rowbase = b * NV + vs * VPB;

    // stage x: 1024 floats = 256 float4
    if (tid < 256) {
        const float4* xsrc = (const float4*)(x + (size_t)rowbase * NFT);
        ((float4*)xs)[tid] = xsrc[tid];
    }
    __syncthreads();

    // phase A
    {
        int c  = tid & 127;
        int rh = tid >> 7;
        if (c < NC) {
            float Wcol[NFT], bias;
            if (c < NP) {
                bias = b_flr[c];
#pragma unroll
                for (int k = 0; k < NFT; ++k) Wcol[k] = W_flr[k * NP + c];
            } else {
                int a = c - NP;
                bias = b_s[a];
#pragma unroll
                for (int k = 0; k < NFT; ++k) Wcol[k] = W_s[k * NA + a];
            }
#pragma unroll
            for (int r0 = 0; r0 < 16; ++r0) {
                int r = rh * 16 + r0;
                float xr[NFT];
#pragma unroll
                for (int q = 0; q < 4; ++q)
                    ((float4*)xr)[q] = ((const float4*)xs[r])[q];
                float acc = bias;
#pragma unroll
                for (int k = 0; k < NFT; ++k)
                    acc = fmaf(xr[k], Wcol[k], acc);
                if (c >= NP) {
                    acc = __expf(-acc * acc);
                    ewbuf[(size_t)(rowbase + r) * NA + (c - NP)] = acc;
                }
                fs[r][c] = acc;
            }
        }
    }
    __syncthreads();

    // phase B: rsplit = tid>>8; unit u = tid&255: a0 = (u>>5)*4, c0 = (u&31)*3
    int rsplit = tid >> 8;
    int u  = tid & 255;
    int a0 = (u >> 5) * 4;
    int c0 = (u & 31) * 3;
    int rb = rsplit * 32;

    float sm[4][3], mx[4][3];
#pragma unroll
    for (int i = 0; i < 4; ++i)
#pragma unroll
        for (int j = 0; j < 3; ++j) { sm[i][j] = 0.f; mx[i][j] = -INFINITY; }

#pragma unroll 4
    for (int r0 = 0; r0 < 32; ++r0) {
        int r = rb + r0;
        float4 e4 = *(const float4*)&fs[r][NP + a0];
        float2 f2 = *(const float2*)&fs[r][c0];
        float f1 = fs[r][c0 + 2];
        float ff[3] = {f2.x, f2.y, f1};
        float ee[4] = {e4.x, e4.y, e4.z, e4.w};
#pragma unroll
        for (int i = 0; i < 4; ++i)
#pragma unroll
            for (int j = 0; j < 3; ++j) {
                float p = ee[i] * ff[j];
                sm[i][j] += p;
                mx[i][j] = fmaxf(mx[i][j], p);
            }
    }

    __syncthreads();   // all fs reads done; comb may overlay

    if (rsplit == 0) {
        float* cb = comb + u * 26;
#pragma unroll
        for (int i = 0; i < 4; ++i) {
            float2 v0 = {sm[i][0], sm[i][1]};
            float2 v1 = {sm[i][2], mx[i][0]};
            float2 v2 = {mx[i][1], mx[i][2]};
            *(float2*)&cb[i * 6]     = v0;
            *(float2*)&cb[i * 6 + 2] = v1;
            *(float2*)&cb[i * 6 + 4] = v2;
        }
    }
    __syncthreads();
    if (rsplit == 1) {
        const float* cb = comb + u * 26;
        float* pb = part + (size_t)((b * NSPLIT + vs) * NA) * NC2;
#pragma unroll
        for (int i = 0; i < 4; ++i) {
            float2 v0 = *(const float2*)&cb[i * 6];
            float2 v1 = *(const float2*)&cb[i * 6 + 2];
            float2 v2 = *(const float2*)&cb[i * 6 + 4];
            float osm0 = v0.x, osm1 = v0.y, osm2 = v1.x;
            float omx0 = v1.y, omx1 = v2.x, omx2 = v2.y;
            int a = a0 + i;
            float m0 = fmaxf(mx[i][0], omx0);
            float m1 = fmaxf(mx[i][1], omx1);
            float m2 = fmaxf(mx[i][2], omx2);
            float s0 = sm[i][0] + osm0;
            float s1 = sm[i][1] + osm1;
            float s2 = sm[i][2] + osm2;
            float2 wm = {m0, m1};
            float2 ws = {s0, s1};
            *(float2*)&pb[a * NC2 + c0] = wm;
            pb[a * NC2 + c0 + 2] = m2;
            *(float2*)&pb[a * NC2 + NC + c0] = ws;
            pb[a * NC2 + NC + c0 + 2] = s2;
        }
    }
}

// ---------------------------------------------------------------------------
// K23: combine NSPLIT partials -> agg (LDS) -> G matmul.
// grid (16 b-pairs, 32 a) x 256: h = tid>>7 selects b = bq*2+h. Both halves
// read the SAME W_out slab (same a) -> W L2 traffic halves.
// ---------------------------------------------------------------------------
__global__ void k23(const float* __restrict__ part,
                    const float* __restrict__ W_out,
                    float* __restrict__ Gp) {
    __shared__ float aggL[2][NC2];
    int bq = blockIdx.x, a = blockIdx.y, tid = threadIdx.x;
    int h = tid >> 7;                 // 0,1
    int t = tid & 127;
    int b = bq * 2 + h;

    const float* pb = part + (size_t)(b * NSPLIT * NA + a) * NC2;
    const size_t stride = (size_t)NA * NC2;

#pragma unroll
    for (int cell = 0; cell < 2; ++cell) {
        int j = t + cell * 128;
        if (j < NC2) {
            if (j < NC) {
                float m = -INFINITY;
#pragma unroll
                for (int vsi = 0; vsi < NSPLIT; ++vsi)
                    m = fmaxf(m, pb[vsi * stride + j]);
                aggL[h][j] = m;
            } else {
                float s = 0.f;
#pragma unroll
                for (int vsi = 0; vsi < NSPLIT; ++vsi)
                    s += pb[vsi * stride + j];
                aggL[h][j] = s * (1.0f / (float)NV);
            }
        }
    }
    __syncthreads();

    {
        int n = t;
        const float* wr = W_out + (size_t)(NFT + a * NC2) * NOUT + n;
        float acc = W_out[(size_t)(NFT + NA * NC2 + a) * NOUT + n];
#pragma unroll 8
        for (int c = 0; c < NC2; ++c)
            acc = fmaf(aggL[h][c], wr[(size_t)c * NOUT], acc);
        Gp[(size_t)(b * NA + a) * NOUT + n] = acc;
    }
}

// ---------------------------------------------------------------------------
// K4 (MFMA): out[b,v,:] = tanh( [x‖ew] @ [W_head;G] + b_out )   (unchanged R8)
// ---------------------------------------------------------------------------
#define MB 64
#define SWZ(r, k)  (((r) << 6) + ((k) ^ (((r) & 7) << 3)))
#define SWZB(n, k) (((n) << 6) + ((k) ^ (((((n) >> 3) & 7) ^ ((n) & 7)) << 3)))

__device__ inline void f2hl(float v, ushort& h, ushort& l) {
    __hip_bfloat16 hb = __float2bfloat16(v);
    float hf = __bfloat162float(hb);
    __hip_bfloat16 lb = __float2bfloat16(v - hf);
    h = *(ushort*)&hb;
    l = *(ushort*)&lb;
}

__global__ void k4_mfma(const float* __restrict__ x,
                        const float* __restrict__ ewbuf,
                        const float* __restrict__ Gp,
                        const float* __restrict__ W_out,
                        const float* __restrict__ b_out,
                        float* __restrict__ out) {
    __shared__ ushort AsH[MB * 64], AsL[MB * 64];     // 8 KB each
    __shared__ ushort BsH[NOUT * 64], BsL[NOUT * 64]; // 16 KB each
    __shared__ float  bs[NOUT];

    int rb = blockIdx.x;          // row-block within batch (0..15)
    int b  = blockIdx.y;
    int tid = threadIdx.x;
    int rowbase = b * NV + rb * MB;

    // ---- stage A: x part (k=0..15) ----
    {
        float4 v = ((const float4*)(x + (size_t)rowbase * NFT))[tid];
        int r = tid >> 2, kq = (tid & 3) * 4;
        float vv[4] = {v.x, v.y, v.z, v.w};
        ushort h[4], l[4];
#pragma unroll
        for (int j = 0; j < 4; ++j) f2hl(vv[j], h[j], l[j]);
        *(uint*)&AsH[SWZ(r, kq)]     = (uint)h[0] | ((uint)h[1] << 16);
        *(uint*)&AsH[SWZ(r, kq + 2)] = (uint)h[2] | ((uint)h[3] << 16);
        *(uint*)&AsL[SWZ(r, kq)]     = (uint)l[0] | ((uint)l[1] << 16);
        *(uint*)&AsL[SWZ(r, kq + 2)] = (uint)l[2] | ((uint)l[3] << 16);
    }
    // ---- stage A: ew part (k=16..47) ----
    {
        const float4* es4 = (const float4*)(ewbuf + (size_t)rowbase * NA);
#pragma unroll
        for (int t = 0; t < 2; ++t) {
            int i = tid * 2 + t;
            float4 v = es4[i];
            int r = i >> 3, kq = 16 + (i & 7) * 4;
            float vv[4] = {v.x, v.y, v.z, v.w};
            ushort h[4], l[4];
#pragma unroll
            for (int j = 0; j < 4; ++j) f2hl(vv[j], h[j], l[j]);
            *(uint*)&AsH[SWZ(r, kq)]     = (uint)h[0] | ((uint)h[1] << 16);
            *(uint*)&AsH[SWZ(r, kq + 2)] = (uint)h[2] | ((uint)h[3] << 16);
            *(uint*)&AsL[SWZ(r, kq)]     = (uint)l[0] | ((uint)l[1] << 16);
            *(uint*)&AsL[SWZ(r, kq + 2)] = (uint)l[2] | ((uint)l[3] << 16);
        }
    }
    // ---- stage A: zero tail (k=48..63) ----
    {
#pragma unroll
        for (int t = 0; t < 2; ++t) {
            int i = tid * 2 + t;
            int r = i >> 3, kq = 48 + (i & 7) * 2;
            *(uint*)&AsH[SWZ(r, kq)] = 0u;
            *(uint*)&AsL[SWZ(r, kq)] = 0u;
        }
    }
    // ---- stage B^T: W_head (k=0..15) ----
    {
#pragma unroll
        for (int t = 0; t < 2; ++t) {
            int i = tid * 2 + t;
            int k = i >> 5, nq = (i & 31) * 4;
            float4 v = ((const float4*)W_out)[i];
            float vv[4] = {v.x, v.y, v.z, v.w};
#pragma unroll
            for (int j = 0; j < 4; ++j) {
                ushort h, l;
                f2hl(vv[j], h, l);
                BsH[SWZB(nq + j, k)] = h;
                BsL[SWZB(nq + j, k)] = l;
            }
        }
    }
    // ---- stage B^T: Gp (k=16..47) ----
    {
        const float4* gp4 = (const float4*)(Gp + (size_t)b * NA * NOUT);
#pragma unroll
        for (int t = 0; t < 4; ++t) {
            int i = tid * 4 + t;
            int a = i >> 5, nq = (i & 31) * 4;
            float4 v = gp4[i];
            int k = 16 + a;
            float vv[4] = {v.x, v.y, v.z, v.w};
#pragma unroll
            for (int j = 0; j < 4; ++j) {
                ushort h, l;
                f2hl(vv[j], h, l);
                BsH[SWZB(nq + j, k)] = h;
                BsL[SWZB(nq + j, k)] = l;
            }
        }
    }
    // ---- stage B^T: zero tail (k=48..63) ----
    {
#pragma unroll
        for (int t = 0; t < 4; ++t) {
            int i = tid * 4 + t;
            int n = i >> 3, kq = 48 + (i & 7) * 2;
            *(uint*)&BsH[SWZB(n, kq)] = 0u;
            *(uint*)&BsL[SWZB(n, kq)] = 0u;
        }
    }
    if (tid < NOUT) bs[tid] = b_out[tid];

    __syncthreads();

    // ---- compute ----
    int w = tid >> 6, lane = tid & 63;
    int r16 = lane & 15, kg = lane >> 4, k0 = kg * 8;
    int arow = w * 16 + r16;

    bf16x8 AH0 = *(const bf16x8*)&AsH[SWZ(arow, k0)];
    bf16x8 AH1 = *(const bf16x8*)&AsH[SWZ(arow, 32 + k0)];
    bf16x8 AL0 = *(const bf16x8*)&AsL[SWZ(arow, k0)];
    bf16x8 AL1 = *(const bf16x8*)&AsL[SWZ(arow, 32 + k0)];

    int orow0 = rowbase + w * 16 + kg * 4;

#pragma unroll
    for (int nt = 0; nt < 8; ++nt) {
        int n = nt * 16 + r16;
        bf16x8 BH0 = *(const bf16x8*)&BsH[SWZB(n, k0)];
        bf16x8 BH1 = *(const bf16x8*)&BsH[SWZB(n, 32 + k0)];
        bf16x8 BL0 = *(const bf16x8*)&BsL[SWZB(n, k0)];
        bf16x8 BL1 = *(const bf16x8*)&BsL[SWZB(n, 32 + k0)];
        float bias = bs[n];
        f32x4 acc = {bias, bias, bias, bias};
        acc = __builtin_amdgcn_mfma_f32_16x16x32_bf16(AH0, BH0, acc, 0, 0, 0);
        acc = __builtin_amdgcn_mfma_f32_16x16x32_bf16(AL0, BH0, acc, 0, 0, 0);
        acc = __builtin_amdgcn_mfma_f32_16x16x32_bf16(AH0, BL0, acc, 0, 0, 0);
        acc = __builtin_amdgcn_mfma_f32_16x16x32_bf16(AH1, BH1, acc, 0, 0, 0);
        acc = __builtin_amdgcn_mfma_f32_16x16x32_bf16(AL1, BH1, acc, 0, 0, 0);
        acc = __builtin_amdgcn_mfma_f32_16x16x32_bf16(AH1, BL1, acc, 0, 0, 0);
#pragma unroll
        for (int rg = 0; rg < 4; ++rg) {
            float s = acc[rg];
            s = fminf(fmaxf(s, -15.f), 15.f);
            float e = __expf(2.f * s);
            out[(size_t)(orow0 + rg) * NOUT + n] =
                (e - 1.f) * __builtin_amdgcn_rcpf(e + 1.f);
        }
    }
}

// ---------------------------------------------------------------------------
extern "C" void kernel_launch(void* const* d_in, const int* in_sizes, int n_in,
                              void* d_out, int out_size, void* d_ws, size_t ws_size,
                              hipStream_t stream) {
    const float* x     = (const float*)d_in[0];
    const float* W_flr = (const float*)d_in[1];
    const float* b_flr = (const float*)d_in[2];
    const float* W_s   = (const float*)d_in[3];
    const float* b_s   = (const float*)d_in[4];
    const float* W_out = (const float*)d_in[5];
    const float* b_out = (const float*)d_in[6];
    float* out = (float*)d_out;

    // workspace layout (floats)
    float* ewbuf = (float*)d_ws;                              // B*V*32     = 1,048,576
    float* part  = ewbuf + (size_t)NB * NV * NA;              // 512*32*192 = 3,145,728
    float* Gp    = part  + (size_t)NB * NSPLIT * NA * NC2;    // B*A*128    =   131,072

    // K2p: grid (B, 16) x 512
    {
        dim3 g(NB, NSPLIT);
        k2p<<<g, 512, 0, stream>>>(x, W_flr, b_flr, W_s, b_s, ewbuf, part);
    }
    // K23: grid (16, 32) x 256
    {
        dim3 g(NB / 2, NA);
        k23<<<g, 256, 0, stream>>>(part, W_out, Gp);
    }
    // K4: grid (16 row-blocks, B) x 256
    {
        dim3 g(NV / MB, NB);
        k4_mfma<<<g, 256, 0, stream>>>(x, ewbuf, Gp, W_out, b_out, out);
    }
}

// Round 13
// 39.096 us; speedup vs baseline: 2.9086x; 1.2129x over previous
//
#include <hip/hip_runtime.h>
#include <hip/hip_bf16.h>
#include <math.h>

#define NB 32      // B
#define NV 1024    // V
#define NFT 16     // F
#define NA 32      // A
#define NP 64      // P
#define NOUT 128   // NF
#define NC 96      // C = P + A
#define NC2 192    // 2C

#define NSPLIT 16            // V splits
#define VPB 64               // rows per block

typedef __attribute__((ext_vector_type(8))) short bf16x8;
typedef __attribute__((ext_vector_type(4))) float f32x4;

// ---------------------------------------------------------------------------
// K2p: fused vertex transform + partial (max,sum) aggregation. (R9 verbatim —
// best measured config, 38.1 us total pipeline)
// ---------------------------------------------------------------------------
__global__ __launch_bounds__(512, 2)
void k2p(const float* __restrict__ x,
         const float* __restrict__ W_flr,
         const float* __restrict__ b_flr,
         const float* __restrict__ W_s,
         const float* __restrict__ b_s,
         float* __restrict__ ewbuf,
         float* __restrict__ part) {
    __shared__ float xs[VPB][NFT];        // 4 KB
    __shared__ float fs[VPB][NC];         // 24 KB

    int b = blockIdx.x, vs = blockIdx.y, tid = threadIdx.x;
    int rowbase = b * NV + vs * VPB;

    if (tid < 256) {
        const float4* xsrc = (const float4*)(x + (size_t)rowbase * NFT);
        ((float4*)xs)[tid] = xsrc[tid];
    }
    __syncthreads();

    // phase A: c = tid&127 (<96 active), rh = tid>>7 -> rows rh*16..+15
    {
        int c  = tid & 127;
        int rh = tid >> 7;
        if (c < NC) {
            float Wcol[NFT], bias;
            if (c < NP) {
                bias = b_flr[c];
#pragma unroll
                for (int k = 0; k < NFT; ++k) Wcol[k] = W_flr[k * NP + c];
            } else {
                int a = c - NP;
                bias = b_s[a];
#pragma unroll
                for (int k = 0; k < NFT; ++k) Wcol[k] = W_s[k * NA + a];
            }
#pragma unroll
            for (int r0 = 0; r0 < 16; ++r0) {
                int r = rh * 16 + r0;
                float xr[NFT];
#pragma unroll
                for (int q = 0; q < 4; ++q)
                    ((float4*)xr)[q] = ((const float4*)xs[r])[q];
                float acc = bias;
#pragma unroll
                for (int k = 0; k < NFT; ++k)
                    acc = fmaf(xr[k], Wcol[k], acc);
                if (c >= NP) {
                    acc = __expf(-acc * acc);
                    ewbuf[(size_t)(rowbase + r) * NA + (c - NP)] = acc;
                }
                fs[r][c] = acc;
            }
        }
    }
    __syncthreads();

    // phase B: thread owns 1a x 6c over all 64 rows
    int a  = tid >> 4;
    int c0 = (tid & 15) * 6;
    int ea = NP + a;

    float sm[6], mx[6];
#pragma unroll
    for (int j = 0; j < 6; ++j) { sm[j] = 0.f; mx[j] = -INFINITY; }

#pragma unroll 4
    for (int r = 0; r < VPB; ++r) {
        float e = fs[r][ea];
        float2 fA = *(const float2*)&fs[r][c0];
        float2 fB = *(const float2*)&fs[r][c0 + 2];
        float2 fC = *(const float2*)&fs[r][c0 + 4];
        float ff[6] = {fA.x, fA.y, fB.x, fB.y, fC.x, fC.y};
#pragma unroll
        for (int j = 0; j < 6; ++j) {
            float p = e * ff[j];
            sm[j] += p;
            mx[j] = fmaxf(mx[j], p);
        }
    }

    float* pb = part + (size_t)((b * NSPLIT + vs) * NA + a) * NC2;
#pragma unroll
    for (int q = 0; q < 3; ++q) {
        float2 vm = {mx[2 * q], mx[2 * q + 1]};
        float2 vsum = {sm[2 * q], sm[2 * q + 1]};
        *(float2*)&pb[c0 + 2 * q]      = vm;
        *(float2*)&pb[NC + c0 + 2 * q] = vsum;
    }
}

// ---------------------------------------------------------------------------
// K23: combine NSPLIT partials -> agg (LDS) -> G matmul. (R9 verbatim)
// ---------------------------------------------------------------------------
__global__ void k23(const float* __restrict__ part,
                    const float* __restrict__ W_out,
                    float* __restrict__ Gp) {
    __shared__ float aggL[NC2];
    int b = blockIdx.x, a = blockIdx.y, tid = threadIdx.x;

    {
        const float* pb = part + (size_t)(b * NSPLIT * NA + a) * NC2 + tid;
        const size_t stride = (size_t)NA * NC2;
        if (tid < NC) {
            float m = -INFINITY;
#pragma unroll
            for (int vsi = 0; vsi < NSPLIT; ++vsi)
                m = fmaxf(m, pb[vsi * stride]);
            aggL[tid] = m;
        } else {
            float s = 0.f;
#pragma unroll
            for (int vsi = 0; vsi < NSPLIT; ++vsi)
                s += pb[vsi * stride];
            aggL[tid] = s * (1.0f / (float)NV);
        }
    }
    __syncthreads();

    if (tid < NOUT) {
        int n = tid;
        const float* wr = W_out + (size_t)(NFT + a * NC2) * NOUT + n;
        float acc = W_out[(size_t)(NFT + NA * NC2 + a) * NOUT + n];
#pragma unroll 8
        for (int c = 0; c < NC2; ++c)
            acc = fmaf(aggL[c], wr[(size_t)c * NOUT], acc);
        Gp[(size_t)(b * NA + a) * NOUT + n] = acc;
    }
}

// ---------------------------------------------------------------------------
// K4 (MFMA, conflict-free layout): out[b,v,:] = tanh([x‖ew]@[W_head;G] + b)
// A fragments loaded DIRECTLY from global into registers (no LDS, no sync):
//   lane (r16,kg) of wave w needs A[w*16+r16][k0..k0+7], k0=kg*8 — that's a
//   16B-aligned float4 pair from x (k<16) / ewbuf (16<=k<48) / zeros (k>=48).
// B stored in FRAGMENT-ORDER LDS: chunk(n,koct) = 8 consecutive k as bf16x8 at
//   index ((koct>>2)*512 + (n>>4)*64 + (koct&3)*16 + (n&15)) * 8 ushorts, so
//   the MFMA read is &Bs[(nt*64 + lane)*8] — lane-linear, conflict-free; the
//   staging writes are lane-linear b128 bursts (canonical free pattern).
// ---------------------------------------------------------------------------
#define MB 64

__device__ inline void f2hl(float v, ushort& h, ushort& l) {
    __hip_bfloat16 hb = __float2bfloat16(v);
    float hf = __bfloat162float(hb);
    __hip_bfloat16 lb = __float2bfloat16(v - hf);
    h = *(ushort*)&hb;
    l = *(ushort*)&lb;
}

__global__ void k4_mfma(const float* __restrict__ x,
                        const float* __restrict__ ewbuf,
                        const float* __restrict__ Gp,
                        const float* __restrict__ W_out,
                        const float* __restrict__ b_out,
                        float* __restrict__ out) {
    __shared__ ushort BsH[1024 * 8];   // 16 KB (1024 chunks x 8 ushorts)
    __shared__ ushort BsL[1024 * 8];   // 16 KB
    __shared__ float  bs[NOUT];

    int rb = blockIdx.x;          // row-block within batch (0..15)
    int b  = blockIdx.y;
    int tid = threadIdx.x;
    int rowbase = b * NV + rb * MB;

    // ---- stage B in fragment-order: 1024 chunks, 4 iters of 256 threads ----
#pragma unroll
    for (int it = 0; it < 4; ++it) {
        int u = it * 256 + tid;           // 0..1023
        int n = u & 127, koct = u >> 7;   // koct 0..7
        float v[8];
        if (koct < 2) {
#pragma unroll
            for (int j = 0; j < 8; ++j)
                v[j] = W_out[(size_t)(koct * 8 + j) * NOUT + n];
        } else if (koct < 6) {
#pragma unroll
            for (int j = 0; j < 8; ++j)
                v[j] = Gp[(size_t)b * NA * NOUT + (size_t)(koct * 8 + j - 16) * NOUT + n];
        } else {
#pragma unroll
            for (int j = 0; j < 8; ++j) v[j] = 0.f;
        }
        ushort h[8], l[8];
#pragma unroll
        for (int j = 0; j < 8; ++j) f2hl(v[j], h[j], l[j]);
        int cidx = ((koct >> 2) * 512) + ((n >> 4) * 64) + ((koct & 3) * 16) + (n & 15);
        *(bf16x8*)&BsH[cidx * 8] = *(bf16x8*)h;
        *(bf16x8*)&BsL[cidx * 8] = *(bf16x8*)l;
    }
    if (tid < NOUT) bs[tid] = b_out[tid];

    // ---- A fragments direct from global (registers only) ----
    int w = tid >> 6, lane = tid & 63;
    int r16 = lane & 15, kg = lane >> 4;
    int arow = w * 16 + r16;
    int grow = rowbase + arow;

    float a0[8], a1[8];
    if (kg < 2) {
        // k = kg*8 .. +7  -> x cols
        *(float4*)&a0[0] = *(const float4*)&x[(size_t)grow * NFT + kg * 8];
        *(float4*)&a0[4] = *(const float4*)&x[(size_t)grow * NFT + kg * 8 + 4];
        // k = 32+kg*8 .. +7 -> ew cols 16+kg*8
        *(float4*)&a1[0] = *(const float4*)&ewbuf[(size_t)grow * NA + 16 + kg * 8];
        *(float4*)&a1[4] = *(const float4*)&ewbuf[(size_t)grow * NA + 16 + kg * 8 + 4];
    } else {
        // k = 16+(kg-2)*8 .. +7 -> ew cols (kg-2)*8
        *(float4*)&a0[0] = *(const float4*)&ewbuf[(size_t)grow * NA + (kg - 2) * 8];
        *(float4*)&a0[4] = *(const float4*)&ewbuf[(size_t)grow * NA + (kg - 2) * 8 + 4];
#pragma unroll
        for (int j = 0; j < 8; ++j) a1[j] = 0.f;   // k = 48..63 zero pad
    }
    ushort ah0[8], al0[8], ah1[8], al1[8];
#pragma unroll
    for (int j = 0; j < 8; ++j) f2hl(a0[j], ah0[j], al0[j]);
#pragma unroll
    for (int j = 0; j < 8; ++j) f2hl(a1[j], ah1[j], al1[j]);
    bf16x8 AH0 = *(bf16x8*)ah0, AL0 = *(bf16x8*)al0;
    bf16x8 AH1 = *(bf16x8*)ah1, AL1 = *(bf16x8*)al1;

    __syncthreads();

    int orow0 = rowbase + w * 16 + kg * 4;

#pragma unroll
    for (int nt = 0; nt < 8; ++nt) {
        int n = nt * 16 + r16;
        bf16x8 BH0 = *(const bf16x8*)&BsH[(nt * 64 + lane) * 8];
        bf16x8 BH1 = *(const bf16x8*)&BsH[(512 + nt * 64 + lane) * 8];
        bf16x8 BL0 = *(const bf16x8*)&BsL[(nt * 64 + lane) * 8];
        bf16x8 BL1 = *(const bf16x8*)&BsL[(512 + nt * 64 + lane) * 8];
        float bias = bs[n];
        f32x4 acc = {bias, bias, bias, bias};
        acc = __builtin_amdgcn_mfma_f32_16x16x32_bf16(AH0, BH0, acc, 0, 0, 0);
        acc = __builtin_amdgcn_mfma_f32_16x16x32_bf16(AL0, BH0, acc, 0, 0, 0);
        acc = __builtin_amdgcn_mfma_f32_16x16x32_bf16(AH0, BL0, acc, 0, 0, 0);
        acc = __builtin_amdgcn_mfma_f32_16x16x32_bf16(AH1, BH1, acc, 0, 0, 0);
        acc = __builtin_amdgcn_mfma_f32_16x16x32_bf16(AL1, BH1, acc, 0, 0, 0);
        acc = __builtin_amdgcn_mfma_f32_16x16x32_bf16(AH1, BL1, acc, 0, 0, 0);
#pragma unroll
        for (int rg = 0; rg < 4; ++rg) {
            float s = acc[rg];
            s = fminf(fmaxf(s, -15.f), 15.f);
            float e = __expf(2.f * s);
            out[(size_t)(orow0 + rg) * NOUT + n] =
                (e - 1.f) * __builtin_amdgcn_rcpf(e + 1.f);
        }
    }
}

// ---------------------------------------------------------------------------
extern "C" void kernel_launch(void* const* d_in, const int* in_sizes, int n_in,
                              void* d_out, int out_size, void* d_ws, size_t ws_size,
                              hipStream_t stream) {
    const float* x     = (const float*)d_in[0];
    const float* W_flr = (const float*)d_in[1];
    const float* b_flr = (const float*)d_in[2];
    const float* W_s   = (const float*)d_in[3];
    const float* b_s   = (const float*)d_in[4];
    const float* W_out = (const float*)d_in[5];
    const float* b_out = (const float*)d_in[6];
    float* out = (float*)d_out;

    // workspace layout (floats)
    float* ewbuf = (float*)d_ws;                              // B*V*32     = 1,048,576
    float* part  = ewbuf + (size_t)NB * NV * NA;              // 512*32*192 = 3,145,728
    float* Gp    = part  + (size_t)NB * NSPLIT * NA * NC2;    // B*A*128    =   131,072

    // K2p: grid (B, 16) x 512
    {
        dim3 g(NB, NSPLIT);
        k2p<<<g, 512, 0, stream>>>(x, W_flr, b_flr, W_s, b_s, ewbuf, part);
    }
    // K23: grid (B, A) x 192
    {
        dim3 g(NB, NA);
        k23<<<g, 192, 0, stream>>>(part, W_out, Gp);
    }
    // K4: grid (16 row-blocks, B) x 256
    {
        dim3 g(NV / MB, NB);
        k4_mfma<<<g, 256, 0, stream>>>(x, ewbuf, Gp, W_out, b_out, out);
    }
}